// Round 1
// baseline (1016.259 us; speedup 1.0000x reference)
//
#include <hip/hip_runtime.h>

#define TT  1024
#define DIN 8

// sigma(x) = 1 / (1 + exp2(-x*log2e))
__device__ __forceinline__ float fsig(float x) {
    float e = __builtin_amdgcn_exp2f(-1.4426950408889634f * x);
    return __builtin_amdgcn_rcpf(1.0f + e);
}
// tanh(x) = 2*sigma(2x) - 1
__device__ __forceinline__ float ftanh_(float x) {
    float e = __builtin_amdgcn_exp2f(-2.8853900817779268f * x);
    return 2.0f * __builtin_amdgcn_rcpf(1.0f + e) - 1.0f;
}
// broadcast lane l's value to all lanes (readlane -> SGPR-resident uniform)
__device__ __forceinline__ float bcastf(float v, int l) {
    return __uint_as_float((unsigned)__builtin_amdgcn_readlane((int)__float_as_uint(v), l));
}
__device__ __forceinline__ void row32(const float* __restrict__ p, float* r) {
#pragma unroll
    for (int q = 0; q < 8; ++q) {
        float4 v = reinterpret_cast<const float4*>(p)[q];
        r[4*q] = v.x; r[4*q+1] = v.y; r[4*q+2] = v.z; r[4*q+3] = v.w;
    }
}

// One wave (64 lanes) per batch element. Lane l owns gate rows l and l+64:
//   low lanes (j=l<32):  i_j (row l)     and g_j (row l+64)
//   high lanes (l=32+j): f_j (row l)     and o_j (row l+64)
// Cell state c1_j / c2_j valid on lane j (high-lane copies are harmless garbage,
// bounded, never read). h broadcast via 32x v_readlane per layer (no LDS, no barriers).
__global__ void __launch_bounds__(64, 1)
lstm_fused(const float* __restrict__ x,
           const float* __restrict__ Wih1, const float* __restrict__ Whh1,
           const float* __restrict__ bih1, const float* __restrict__ bhh1,
           const float* __restrict__ Wih2, const float* __restrict__ Whh2,
           const float* __restrict__ bih2, const float* __restrict__ bhh2,
           const float* __restrict__ Wlin, const float* __restrict__ blin,
           float* __restrict__ out)
{
    const int b    = blockIdx.x;
    const int lane = threadIdx.x;
    const bool hi  = (lane >= 32);
    const int glo  = lane;
    const int ghi  = lane + 64;

    // ---- weights -> registers (one-time preamble) ----
    float wih1_lo[DIN], wih1_hi[DIN];
#pragma unroll
    for (int k = 0; k < DIN; ++k) {
        wih1_lo[k] = Wih1[glo*DIN + k];
        wih1_hi[k] = Wih1[ghi*DIN + k];
    }
    float whh1_lo[32], whh1_hi[32], wih2_lo[32], wih2_hi[32], whh2_lo[32], whh2_hi[32];
    row32(Whh1 + glo*32, whh1_lo); row32(Whh1 + ghi*32, whh1_hi);
    row32(Wih2 + glo*32, wih2_lo); row32(Wih2 + ghi*32, wih2_hi);
    row32(Whh2 + glo*32, whh2_lo); row32(Whh2 + ghi*32, whh2_hi);

    const float b1lo = bih1[glo] + bhh1[glo];
    const float b1hi = bih1[ghi] + bhh1[ghi];
    const float b2lo = bih2[glo] + bhh2[glo];
    const float b2hi = bih2[ghi] + bhh2[ghi];

    // output linear: lane computes out col `lane`, plus col `lane+64` if lane<16
    const int o1 = (lane < 16) ? (lane + 64) : 79;  // clamp for safe (unused) loads
    float wl0[32], wl1[32];
    row32(Wlin + lane*32, wl0);
    row32(Wlin + o1*32,   wl1);
    const float bl0 = blin[lane];
    const float bl1 = blin[o1];

    // ---- recurrent state ----
    float h1r[32], h2r[32];
#pragma unroll
    for (int k = 0; k < 32; ++k) { h1r[k] = 0.f; h2r[k] = 0.f; }
    float c1 = 0.f, c2 = 0.f;

    const float* __restrict__ xb = x   + (size_t)b * (TT*DIN);
    float* __restrict__ outb     = out + (size_t)b * (TT*80);

    const int src = (lane & 31) | 32;   // partner high lane for shuffles

#pragma unroll 2
    for (int t = 0; t < TT; ++t) {
        float xk[DIN];
        {
            float4 a = reinterpret_cast<const float4*>(xb + t*DIN)[0];
            float4 c = reinterpret_cast<const float4*>(xb + t*DIN)[1];
            xk[0]=a.x; xk[1]=a.y; xk[2]=a.z; xk[3]=a.w;
            xk[4]=c.x; xk[5]=c.y; xk[6]=c.z; xk[7]=c.w;
        }

        // ---- layer 1 gates (h-part first: covers x load latency) ----
        float plo0 = b1lo, plo1 = 0.f, phi0 = b1hi, phi1 = 0.f;
#pragma unroll
        for (int k = 0; k < 32; k += 2) {
            plo0 += whh1_lo[k]   * h1r[k];
            plo1 += whh1_lo[k+1] * h1r[k+1];
            phi0 += whh1_hi[k]   * h1r[k];
            phi1 += whh1_hi[k+1] * h1r[k+1];
        }
#pragma unroll
        for (int k = 0; k < DIN; k += 2) {
            plo0 += wih1_lo[k]   * xk[k];
            plo1 += wih1_lo[k+1] * xk[k+1];
            phi0 += wih1_hi[k]   * xk[k];
            phi1 += wih1_hi[k+1] * xk[k+1];
        }
        const float plo = plo0 + plo1, phi = phi0 + phi1;

        // A = sigma(plo): sigma(i) on low, sigma(f) on high
        // B = tanh(phi) on low (g), sigma(phi) on high (o)   [branchless]
        float A = fsig(plo);
        float u = hi ? phi : (phi + phi);
        float S = fsig(u);
        float B = hi ? S : (S + S - 1.0f);
        float sf = __shfl(A, src);   // sigma(f_j) on every lane
        float so = __shfl(B, src);   // sigma(o_j) on every lane
        c1 = sf * c1 + A * B;        // valid on low lanes
        float h1v = so * ftanh_(c1); // h1_j on low lanes
#pragma unroll
        for (int k = 0; k < 32; ++k) h1r[k] = bcastf(h1v, k);

        // ---- layer 2 gates (h2-part first: h2r ready since last step) ----
        float qlo0 = b2lo, qlo1 = 0.f, qhi0 = b2hi, qhi1 = 0.f;
#pragma unroll
        for (int k = 0; k < 32; k += 2) {
            qlo0 += whh2_lo[k]   * h2r[k];
            qlo1 += whh2_lo[k+1] * h2r[k+1];
            qhi0 += whh2_hi[k]   * h2r[k];
            qhi1 += whh2_hi[k+1] * h2r[k+1];
        }
#pragma unroll
        for (int k = 0; k < 32; k += 2) {
            qlo0 += wih2_lo[k]   * h1r[k];
            qlo1 += wih2_lo[k+1] * h1r[k+1];
            qhi0 += wih2_hi[k]   * h1r[k];
            qhi1 += wih2_hi[k+1] * h1r[k+1];
        }
        const float qlo = qlo0 + qlo1, qhi = qhi0 + qhi1;

        float A2 = fsig(qlo);
        float u2 = hi ? qhi : (qhi + qhi);
        float S2 = fsig(u2);
        float B2 = hi ? S2 : (S2 + S2 - 1.0f);
        float sf2 = __shfl(A2, src);
        float so2 = __shfl(B2, src);
        c2 = sf2 * c2 + A2 * B2;
        float h2v = so2 * ftanh_(c2);
#pragma unroll
        for (int k = 0; k < 32; ++k) h2r[k] = bcastf(h2v, k);

        // ---- fused output linear: out[b][t][o] = h2 . Wlin[o] + blin[o] ----
        float a0 = bl0, a0b = 0.f, a1 = bl1, a1b = 0.f;
#pragma unroll
        for (int k = 0; k < 32; k += 2) {
            a0  += wl0[k]   * h2r[k];
            a0b += wl0[k+1] * h2r[k+1];
            a1  += wl1[k]   * h2r[k];
            a1b += wl1[k+1] * h2r[k+1];
        }
        float* op = outb + t*80;
        op[lane] = a0 + a0b;
        if (lane < 16) op[64 + lane] = a1 + a1b;
    }
}

extern "C" void kernel_launch(void* const* d_in, const int* in_sizes, int n_in,
                              void* d_out, int out_size, void* d_ws, size_t ws_size,
                              hipStream_t stream) {
    const float* x    = (const float*)d_in[0];
    const float* Wih1 = (const float*)d_in[1];
    const float* Whh1 = (const float*)d_in[2];
    const float* bih1 = (const float*)d_in[3];
    const float* bhh1 = (const float*)d_in[4];
    const float* Wih2 = (const float*)d_in[5];
    const float* Whh2 = (const float*)d_in[6];
    const float* bih2 = (const float*)d_in[7];
    const float* bhh2 = (const float*)d_in[8];
    const float* Wlin = (const float*)d_in[9];
    const float* blin = (const float*)d_in[10];

    const int B = in_sizes[0] / (TT * DIN);   // 256

    hipLaunchKernelGGL(lstm_fused, dim3(B), dim3(64), 0, stream,
                       x, Wih1, Whh1, bih1, bhh1,
                       Wih2, Whh2, bih2, bhh2, Wlin, blin,
                       (float*)d_out);
}

// Round 2
// 903.843 us; speedup vs baseline: 1.1244x; 1.1244x over previous
//
#include <hip/hip_runtime.h>

#define TT  1024
#define DIN 8

// Pin a value into a VGPR: asm-produced values cannot be rematerialized, so the
// allocator must keep them register-resident across the whole t-loop.
#define PIN(v) asm volatile("" : "+v"(v))

// sigma(x) = 1 / (1 + exp2(-x*log2e))
__device__ __forceinline__ float fsig(float x) {
    float e = __builtin_amdgcn_exp2f(-1.4426950408889634f * x);
    return __builtin_amdgcn_rcpf(1.0f + e);
}
// tanh(x) = 2*sigma(2x) - 1
__device__ __forceinline__ float ftanh_(float x) {
    float e = __builtin_amdgcn_exp2f(-2.8853900817779268f * x);
    return 2.0f * __builtin_amdgcn_rcpf(1.0f + e) - 1.0f;
}
// broadcast lane l's value to all lanes (readlane -> SGPR-resident uniform)
__device__ __forceinline__ float bcastf(float v, int l) {
    return __uint_as_float((unsigned)__builtin_amdgcn_readlane((int)__float_as_uint(v), l));
}
// swap with neighbor lane (lane^1) via DPP quad_perm(1,0,3,2) — VALU latency,
// replaces ds_bpermute-based __shfl on the serial path.
__device__ __forceinline__ float dppswap(float v) {
    int r = __builtin_amdgcn_update_dpp(0, (int)__float_as_uint(v),
                                        0xB1 /*quad_perm(1,0,3,2)*/, 0xF, 0xF, true);
    return __uint_as_float((unsigned)r);
}
__device__ __forceinline__ void row32(const float* __restrict__ p, float* r) {
#pragma unroll
    for (int qq = 0; qq < 8; ++qq) {
        float4 v = reinterpret_cast<const float4*>(p)[qq];
        r[4*qq] = v.x; r[4*qq+1] = v.y; r[4*qq+2] = v.z; r[4*qq+3] = v.w;
    }
}

// One wave per batch element. Unit j = lane>>1 (0..31), parity q = lane&1.
//   even lane (q=0): gate rows j      (i) and 64+j (g)
//   odd  lane (q=1): gate rows 32+j   (f) and 96+j (o)
// Cell update needs (si,sf,tg,so) on both lanes of a pair -> 2 DPP neighbor
// swaps per layer. Both lanes of a pair then hold h_j; broadcast via 32x
// v_readlane(, 2k) per layer into SGPRs (legal as the one scalar FMA operand).
__global__ void __launch_bounds__(64, 1)
lstm_fused(const float* __restrict__ x,
           const float* __restrict__ Wih1, const float* __restrict__ Whh1,
           const float* __restrict__ bih1, const float* __restrict__ bhh1,
           const float* __restrict__ Wih2, const float* __restrict__ Whh2,
           const float* __restrict__ bih2, const float* __restrict__ bhh2,
           const float* __restrict__ Wlin, const float* __restrict__ blin,
           float* __restrict__ out)
{
    const int b    = blockIdx.x;
    const int lane = threadIdx.x;
    const int q    = lane & 1;
    const int j    = lane >> 1;
    const int r0   = q ? (32 + j) : j;          // i | f
    const int r1   = q ? (96 + j) : (64 + j);   // g | o

    // ---- weights -> registers (one-time preamble) ----
    float wx0[DIN], wx1[DIN];
#pragma unroll
    for (int k = 0; k < DIN; ++k) {
        wx0[k] = Wih1[r0*DIN + k];
        wx1[k] = Wih1[r1*DIN + k];
    }
    float wh0[32], wh1c[32];      // Whh1 rows r0, r1
    row32(Whh1 + r0*32, wh0);  row32(Whh1 + r1*32, wh1c);
    float v20[32], v21[32];       // Wih2 rows (input = h1)
    row32(Wih2 + r0*32, v20);  row32(Wih2 + r1*32, v21);
    float u20[32], u21[32];       // Whh2 rows (input = h2)
    row32(Whh2 + r0*32, u20);  row32(Whh2 + r1*32, u21);

    float bA1 = bih1[r0] + bhh1[r0];
    float bB1 = bih1[r1] + bhh1[r1];
    float bA2 = bih2[r0] + bhh2[r0];
    float bB2 = bih2[r1] + bhh2[r1];

    // output linear: lane -> out col lane, plus col 64+lane for lane<16
    const int o1 = (lane < 16) ? (lane + 64) : 79;  // clamp: loads valid, unused
    float wl0[32], wl1[32];
    row32(Wlin + lane*32, wl0);
    row32(Wlin + o1*32,   wl1);
    float bl0 = blin[lane];
    float bl1 = blin[o1];

    // ---- pin every loop-invariant weight/bias into a VGPR ----
#pragma unroll
    for (int k = 0; k < DIN; ++k) { PIN(wx0[k]); PIN(wx1[k]); }
#pragma unroll
    for (int k = 0; k < 32; ++k) {
        PIN(wh0[k]); PIN(wh1c[k]); PIN(v20[k]); PIN(v21[k]);
        PIN(u20[k]); PIN(u21[k]);  PIN(wl0[k]); PIN(wl1[k]);
    }
    PIN(bA1); PIN(bB1); PIN(bA2); PIN(bB2); PIN(bl0); PIN(bl1);

    // ---- recurrent state (h in SGPRs via readlane, c per-lane) ----
    float h1s[32], h2s[32];
#pragma unroll
    for (int k = 0; k < 32; ++k) { h1s[k] = 0.f; h2s[k] = 0.f; }
    float c1 = 0.f, c2 = 0.f;

    const float* __restrict__ xb = x   + (size_t)b * (TT*DIN);
    float* __restrict__ outb     = out + (size_t)b * (TT*80);

#pragma unroll 1
    for (int tt = 0; tt < TT; tt += 8) {
        // tile prefetch: 8 steps of x (all lanes load same addr -> broadcast)
        float4 xq[16];
#pragma unroll
        for (int i = 0; i < 16; ++i)
            xq[i] = reinterpret_cast<const float4*>(xb + tt*DIN)[i];

#pragma unroll
        for (int s = 0; s < 8; ++s) {
            const int t = tt + s;
            float xk[DIN];
            xk[0]=xq[2*s].x; xk[1]=xq[2*s].y; xk[2]=xq[2*s].z; xk[3]=xq[2*s].w;
            xk[4]=xq[2*s+1].x; xk[5]=xq[2*s+1].y; xk[6]=xq[2*s+1].z; xk[7]=xq[2*s+1].w;

            // ---- layer 1 gates ----
            float p0a = bA1, p0b = 0.f, p1a = bB1, p1b = 0.f;
#pragma unroll
            for (int k = 0; k < 32; k += 2) {
                p0a += wh0[k]    * h1s[k];
                p0b += wh0[k+1]  * h1s[k+1];
                p1a += wh1c[k]   * h1s[k];
                p1b += wh1c[k+1] * h1s[k+1];
            }
#pragma unroll
            for (int k = 0; k < DIN; k += 2) {
                p0a += wx0[k]   * xk[k];
                p0b += wx0[k+1] * xk[k+1];
                p1a += wx1[k]   * xk[k];
                p1b += wx1[k+1] * xk[k+1];
            }
            const float p0 = p0a + p0b, p1 = p1a + p1b;

            float A  = fsig(p0);                  // sig(i) even | sig(f) odd
            float uu = q ? p1 : (p1 + p1);
            float S  = fsig(uu);
            float Bv = q ? S : (S + S - 1.0f);    // sig(o) odd | tanh(g) even
            float An = dppswap(A), Bn = dppswap(Bv);
            float si = q ? An : A;
            float sf = q ? A  : An;
            float tg = q ? Bn : Bv;
            float so = q ? Bv : Bn;
            c1 = sf * c1 + si * tg;
            float h1v = so * ftanh_(c1);          // h1_j on both pair lanes

            // ---- layer 2: h2-part first (doesn't need the new h1) ----
            float q0a = bA2, q0b = 0.f, q1a = bB2, q1b = 0.f;
#pragma unroll
            for (int k = 0; k < 32; k += 2) {
                q0a += u20[k]   * h2s[k];
                q0b += u20[k+1] * h2s[k+1];
                q1a += u21[k]   * h2s[k];
                q1b += u21[k+1] * h2s[k+1];
            }
            // broadcast new h1 (32x readlane from even lanes)
            float nh1[32];
#pragma unroll
            for (int k = 0; k < 32; ++k) nh1[k] = bcastf(h1v, 2*k);
#pragma unroll
            for (int k = 0; k < 32; k += 2) {
                q0a += v20[k]   * nh1[k];
                q0b += v20[k+1] * nh1[k+1];
                q1a += v21[k]   * nh1[k];
                q1b += v21[k+1] * nh1[k+1];
            }
            const float q0 = q0a + q0b, q1 = q1a + q1b;

            float A2  = fsig(q0);
            float uu2 = q ? q1 : (q1 + q1);
            float S2  = fsig(uu2);
            float B2  = q ? S2 : (S2 + S2 - 1.0f);
            float An2 = dppswap(A2), Bn2 = dppswap(B2);
            float si2 = q ? An2 : A2;
            float sf2 = q ? A2  : An2;
            float tg2 = q ? Bn2 : B2;
            float so2 = q ? B2  : Bn2;
            c2 = sf2 * c2 + si2 * tg2;
            float h2v = so2 * ftanh_(c2);

            float nh2[32];
#pragma unroll
            for (int k = 0; k < 32; ++k) nh2[k] = bcastf(h2v, 2*k);
#pragma unroll
            for (int k = 0; k < 32; ++k) { h1s[k] = nh1[k]; h2s[k] = nh2[k]; }

            // ---- fused output linear ----
            float a0 = bl0, a0b = 0.f, a1 = bl1, a1b = 0.f;
#pragma unroll
            for (int k = 0; k < 32; k += 2) {
                a0  += wl0[k]   * h2s[k];
                a0b += wl0[k+1] * h2s[k+1];
                a1  += wl1[k]   * h2s[k];
                a1b += wl1[k+1] * h2s[k+1];
            }
            float* op = outb + t*80;
            op[lane] = a0 + a0b;
            if (lane < 16) op[64 + lane] = a1 + a1b;
        }
    }
}

extern "C" void kernel_launch(void* const* d_in, const int* in_sizes, int n_in,
                              void* d_out, int out_size, void* d_ws, size_t ws_size,
                              hipStream_t stream) {
    const float* x    = (const float*)d_in[0];
    const float* Wih1 = (const float*)d_in[1];
    const float* Whh1 = (const float*)d_in[2];
    const float* bih1 = (const float*)d_in[3];
    const float* bhh1 = (const float*)d_in[4];
    const float* Wih2 = (const float*)d_in[5];
    const float* Whh2 = (const float*)d_in[6];
    const float* bih2 = (const float*)d_in[7];
    const float* bhh2 = (const float*)d_in[8];
    const float* Wlin = (const float*)d_in[9];
    const float* blin = (const float*)d_in[10];

    const int B = in_sizes[0] / (TT * DIN);   // 256

    hipLaunchKernelGGL(lstm_fused, dim3(B), dim3(64), 0, stream,
                       x, Wih1, Whh1, bih1, bhh1,
                       Wih2, Whh2, bih2, bhh2, Wlin, blin,
                       (float*)d_out);
}

// Round 4
// 743.147 us; speedup vs baseline: 1.3675x; 1.2162x over previous
//
#include <hip/hip_runtime.h>

#define TT   1024
#define DIN  8
#define TILE 2

// sigma(x) = 1 / (1 + exp2(-x*log2e))
__device__ __forceinline__ float fsig(float x) {
    float e = __builtin_amdgcn_exp2f(-1.4426950408889634f * x);
    return __builtin_amdgcn_rcpf(1.0f + e);
}
// tanh(x) = 2*sigma(2x) - 1
__device__ __forceinline__ float ftanh_(float x) {
    float e = __builtin_amdgcn_exp2f(-2.8853900817779268f * x);
    return 2.0f * __builtin_amdgcn_rcpf(1.0f + e) - 1.0f;
}
__device__ __forceinline__ void row32(const float* __restrict__ p, float* r) {
#pragma unroll
    for (int qq = 0; qq < 8; ++qq) {
        float4 v = reinterpret_cast<const float4*>(p)[qq];
        r[4*qq] = v.x; r[4*qq+1] = v.y; r[4*qq+2] = v.z; r[4*qq+3] = v.w;
    }
}

// 2 waves per batch element (block = 128 threads).
// Wave w owns units w*16..w*16+15. Lane l: jp = l&15 (local unit), grp = l>>4
// in {i,f,g,o}. Lane computes gate row R = grp*32 + (w*16+jp) of each layer
// -> ONE 40-wide L1 row + ONE 64-wide L2 row + ONE 32-wide out column per
// lane (~139 weight floats: fits in registers, unlike the 278 of the 1-wave
// layout). h replicated to all lanes via LDS broadcast reads (uniform addr),
// ONE __syncthreads per step; out-linear pipelined by one step so the h2
// exchange latency hides under the next step's L1 dot.
__global__ void __launch_bounds__(128, 1)
lstm_fused(const float* __restrict__ x,
           const float* __restrict__ Wih1, const float* __restrict__ Whh1,
           const float* __restrict__ bih1, const float* __restrict__ bhh1,
           const float* __restrict__ Wih2, const float* __restrict__ Whh2,
           const float* __restrict__ bih2, const float* __restrict__ bhh2,
           const float* __restrict__ Wlin, const float* __restrict__ blin,
           float* __restrict__ out)
{
    const int tid  = threadIdx.x;
    const int w    = tid >> 6;          // wave 0/1
    const int l    = tid & 63;          // lane in wave
    const int jp   = l & 15;            // local unit 0..15
    const int grp  = l >> 4;            // 0=i 1=f 2=g 3=o
    const int unit = w*16 + jp;         // global unit 0..31
    const int R    = grp*32 + unit;     // gate row 0..127
    const bool isg = (grp == 2);
    const int b    = blockIdx.x;

    // h exchange buffers: [0..1] = h1 by parity, [2..3] = h2 by parity
    __shared__ float hb[4][32];
    ((float*)hb)[tid] = 0.f;

    // ---- per-lane weights (one-time) ----
    float wxr[DIN];
#pragma unroll
    for (int k = 0; k < DIN; ++k) wxr[k] = Wih1[R*DIN + k];
    float whr[32], w2r[32], u2r[32];
    row32(Whh1 + R*32, whr);   // L1 h-weights
    row32(Wih2 + R*32, w2r);   // L2 input(h1)-weights
    row32(Whh2 + R*32, u2r);   // L2 h2-weights
    const float br1 = bih1[R] + bhh1[R];
    const float br2 = bih2[R] + bhh2[R];

    // output linear: wave w covers cols w*40 .. w*40+39 on lanes 0..39
    const int  col      = w*40 + l;
    const int  col_ld   = (col < 80) ? col : 79;   // clamp (loads valid, unused)
    const bool do_store = (l < 40);
    float wlc[32];
    row32(Wlin + col_ld*32, wlc);
    const float blc = blin[col_ld];

    // ---- recurrent state ----
    float h1r[32], h2r[32];
#pragma unroll
    for (int k = 0; k < 32; ++k) { h1r[k] = 0.f; h2r[k] = 0.f; }
    float c1 = 0.f, c2 = 0.f;

    const float* __restrict__ xb = x   + (size_t)b * (TT*DIN);
    float* __restrict__ outb     = out + (size_t)b * (TT*80);

    __syncthreads();   // hb zero-init visible

#pragma unroll 1
    for (int tt = 0; tt < TT; tt += TILE) {
        // x tile prefetch (uniform loads, broadcast to all lanes)
        float4 xq[2*TILE];
#pragma unroll
        for (int i = 0; i < 2*TILE; ++i)
            xq[i] = reinterpret_cast<const float4*>(xb + tt*DIN)[i];

#pragma unroll
        for (int s = 0; s < TILE; ++s) {
            const int t = tt + s;
            const int p = t & 1;
            float xk[DIN];
            xk[0]=xq[2*s].x;   xk[1]=xq[2*s].y;   xk[2]=xq[2*s].z;   xk[3]=xq[2*s].w;
            xk[4]=xq[2*s+1].x; xk[5]=xq[2*s+1].y; xk[6]=xq[2*s+1].z; xk[7]=xq[2*s+1].w;

            // ---- L1 gate row (40 FMA) ----
            float g0 = br1, g1 = 0.f;
#pragma unroll
            for (int k = 0; k < 32; k += 2) {
                g0 += whr[k]   * h1r[k];
                g1 += whr[k+1] * h1r[k+1];
            }
#pragma unroll
            for (int k = 0; k < DIN; k += 2) {
                g0 += wxr[k]   * xk[k];
                g1 += wxr[k+1] * xk[k+1];
            }
            const float gg = g0 + g1;
            float uu = isg ? (gg + gg) : gg;
            float S  = fsig(uu);
            float a  = isg ? (S + S - 1.0f) : S;   // tanh for g-gate, sigmoid else

            // gather i,f,g,o of my unit (intra-wave)
            float ia = __shfl(a, jp);
            float fa = __shfl(a, jp + 16);
            float tg = __shfl(a, jp + 32);
            float oa = __shfl(a, jp + 48);
            c1 = fa * c1 + ia * tg;                // replicated across 4 grp lanes
            float h1v = oa * ftanh_(c1);
            if (l < 16) hb[p][w*16 + l] = h1v;

            __syncthreads();   // h1(t) visible; h2(t-1) visible since sync(t-1)

            // ---- replicated h via LDS broadcast (uniform addr) ----
#pragma unroll
            for (int qk = 0; qk < 8; ++qk) {
                float4 v1 = reinterpret_cast<const float4*>(hb[p])[qk];
                h1r[4*qk]=v1.x; h1r[4*qk+1]=v1.y; h1r[4*qk+2]=v1.z; h1r[4*qk+3]=v1.w;
                float4 v2 = reinterpret_cast<const float4*>(hb[2 + (p^1)])[qk];
                h2r[4*qk]=v2.x; h2r[4*qk+1]=v2.y; h2r[4*qk+2]=v2.z; h2r[4*qk+3]=v2.w;
            }

            // ---- L2 gate row (64 FMA) + out(t-1) column (32 FMA) ----
            float q0 = br2, q1 = 0.f;
            float o0 = blc, o1v = 0.f;
#pragma unroll
            for (int k = 0; k < 32; k += 2) {
                q0  += u2r[k]   * h2r[k];
                q1  += u2r[k+1] * h2r[k+1];
                o0  += wlc[k]   * h2r[k];
                o1v += wlc[k+1] * h2r[k+1];
            }
#pragma unroll
            for (int k = 0; k < 32; k += 2) {
                q0 += w2r[k]   * h1r[k];
                q1 += w2r[k+1] * h1r[k+1];
            }
            const float g2 = q0 + q1;
            float uu2 = isg ? (g2 + g2) : g2;
            float S2  = fsig(uu2);
            float a2  = isg ? (S2 + S2 - 1.0f) : S2;

            float ia2 = __shfl(a2, jp);
            float fa2 = __shfl(a2, jp + 16);
            float tg2 = __shfl(a2, jp + 32);
            float oa2 = __shfl(a2, jp + 48);
            c2 = fa2 * c2 + ia2 * tg2;
            float h2v = oa2 * ftanh_(c2);
            if (l < 16) hb[2 + p][w*16 + l] = h2v;   // consumed after sync(t+1)

            // pipelined output store for step t-1
            if (do_store && t > 0)
                outb[(size_t)(t-1)*80 + col] = o0 + o1v;
        }
    }

    // ---- epilogue: out(T-1) ----
    __syncthreads();
    {
        const int p = (TT - 1) & 1;
        float hr[32];
#pragma unroll
        for (int qk = 0; qk < 8; ++qk) {
            float4 v2 = reinterpret_cast<const float4*>(hb[2 + p])[qk];
            hr[4*qk]=v2.x; hr[4*qk+1]=v2.y; hr[4*qk+2]=v2.z; hr[4*qk+3]=v2.w;
        }
        float o0 = blc, o1v = 0.f;
#pragma unroll
        for (int k = 0; k < 32; k += 2) {
            o0  += wlc[k]   * hr[k];
            o1v += wlc[k+1] * hr[k+1];
        }
        if (do_store)
            outb[(size_t)(TT-1)*80 + col] = o0 + o1v;
    }
}

extern "C" void kernel_launch(void* const* d_in, const int* in_sizes, int n_in,
                              void* d_out, int out_size, void* d_ws, size_t ws_size,
                              hipStream_t stream) {
    const float* x    = (const float*)d_in[0];
    const float* Wih1 = (const float*)d_in[1];
    const float* Whh1 = (const float*)d_in[2];
    const float* bih1 = (const float*)d_in[3];
    const float* bhh1 = (const float*)d_in[4];
    const float* Wih2 = (const float*)d_in[5];
    const float* Whh2 = (const float*)d_in[6];
    const float* bih2 = (const float*)d_in[7];
    const float* bhh2 = (const float*)d_in[8];
    const float* Wlin = (const float*)d_in[9];
    const float* blin = (const float*)d_in[10];

    const int B = in_sizes[0] / (TT * DIN);   // 256

    hipLaunchKernelGGL(lstm_fused, dim3(B), dim3(128), 0, stream,
                       x, Wih1, Whh1, bih1, bhh1,
                       Wih2, Whh2, bih2, bhh2, Wlin, blin,
                       (float*)d_out);
}

// Round 5
// 644.603 us; speedup vs baseline: 1.5766x; 1.1529x over previous
//
#include <hip/hip_runtime.h>

#define TT  1024
#define DIN 8

// sigma(x) = 1 / (1 + exp2(-x*log2e))
__device__ __forceinline__ float fsig(float x) {
    float e = __builtin_amdgcn_exp2f(-1.4426950408889634f * x);
    return __builtin_amdgcn_rcpf(1.0f + e);
}
// tanh(x) = 2*sigma(2x) - 1
__device__ __forceinline__ float ftanh_(float x) {
    float e = __builtin_amdgcn_exp2f(-2.8853900817779268f * x);
    return 2.0f * __builtin_amdgcn_rcpf(1.0f + e) - 1.0f;
}
__device__ __forceinline__ void row32(const float* __restrict__ p, float* r) {
#pragma unroll
    for (int qq = 0; qq < 8; ++qq) {
        float4 v = reinterpret_cast<const float4*>(p)[qq];
        r[4*qq]=v.x; r[4*qq+1]=v.y; r[4*qq+2]=v.z; r[4*qq+3]=v.w;
    }
}
__device__ __forceinline__ void lds32(const volatile float* p, float* r) {
#pragma unroll
    for (int qq = 0; qq < 8; ++qq) {
        float4 v = reinterpret_cast<const float4*>(const_cast<const float*>(p))[qq];
        r[4*qq]=v.x; r[4*qq+1]=v.y; r[4*qq+2]=v.z; r[4*qq+3]=v.w;
    }
}

// 4 waves per batch element (block = 256), layer-pipelined with skew:
//   waves 0-1: layer-1 gate rows (1 row/lane: 8+32 wts) + output linear
//              (32 wts, lanes<40 of each wave -> cols w*40+l), out is one
//              pipeline stage behind h2.
//   waves 2-3: layer-2 gate rows (1 row/lane: 32+32 wts).
// At iter t: L1 computes h1(t) from h1(t-1),x(t); L2 computes h2(t-1) from
// h1(t-1),h2(t-2); L1 also emits out(t-2) from h2(t-2). One barrier/iter.
// Per-lane persistent weights <= 74 floats -> fits residency (round-4 showed
// the allocator keeps ~112 live; 140 did not fit and was re-fetched per step).
__global__ void __launch_bounds__(256, 1)
lstm_pipe(const float* __restrict__ x,
          const float* __restrict__ Wih1, const float* __restrict__ Whh1,
          const float* __restrict__ bih1, const float* __restrict__ bhh1,
          const float* __restrict__ Wih2, const float* __restrict__ Whh2,
          const float* __restrict__ bih2, const float* __restrict__ bhh2,
          const float* __restrict__ Wlin, const float* __restrict__ blin,
          float* __restrict__ out)
{
    const int tid = threadIdx.x;
    const int wv  = tid >> 6;          // wave 0..3
    const int l   = tid & 63;          // lane
    const int jp  = l & 15;            // local unit 0..15
    const int grp = l >> 4;            // 0=i 1=f 2=g 3=o
    const int b   = blockIdx.x;

    const bool isL1 = (wv < 2);
    const int  wl   = isL1 ? wv : (wv - 2);   // wave index within its pair
    const int  unit = wl*16 + jp;             // hidden unit 0..31
    const int  R    = grp*32 + unit;          // gate row 0..127
    const bool isg  = (grp == 2);

    // h exchange: hb1[parity][32] = h1, hb2[parity][32] = h2
    __shared__ float hb1[2][32];
    __shared__ float hb2[2][32];
    if (tid < 64)       ((float*)hb1)[tid]      = 0.f;
    else if (tid < 128) ((float*)hb2)[tid - 64] = 0.f;

    // ---- per-lane weights (wave-uniform branch; arrays unify) ----
    float wa[32];      // L1: Whh1 row R      | L2: Wih2 row R (h1-input wts)
    float wb[32];      // L1: Wlin out column | L2: Whh2 row R (h2 wts)
    float wx[DIN];     // L1 only: Wih1 row R
    float bias, obias;
    int   ocol = 0;
    bool  ostore = false;

    if (isL1) {
#pragma unroll
        for (int k = 0; k < DIN; ++k) wx[k] = Wih1[R*DIN + k];
        row32(Whh1 + R*32, wa);
        bias = bih1[R] + bhh1[R];
        ocol   = wl*40 + l;                  // wave0: 0..39, wave1: 40..79
        ostore = (l < 40);
        const int oc = ostore ? ocol : 79;   // clamp (loads valid, unused)
        row32(Wlin + oc*32, wb);
        obias = blin[oc];
    } else {
#pragma unroll
        for (int k = 0; k < DIN; ++k) wx[k] = 0.f;
        row32(Wih2 + R*32, wa);
        row32(Whh2 + R*32, wb);
        bias  = bih2[R] + bhh2[R];
        obias = 0.f;
    }

    float c = 0.f;   // c1 on L1 lanes, c2 on L2 lanes (replicated per grp-quad)

    const float* __restrict__ xb = x   + (size_t)b * (TT*DIN);
    float* __restrict__ outb     = out + (size_t)b * (TT*80);

    __syncthreads();   // zero-init visible

#pragma unroll 1
    for (int t = 0; t <= TT + 1; ++t) {
        const int pm1 = (t - 1) & 1;
        const int p0  = t & 1;

        // published state (uniform-address LDS reads -> broadcast, no conflicts)
        float hA[32];   // h1(t-1)
        float hB[32];   // h2(t-2)
        lds32(hb1[pm1], hA);
        lds32(hb2[p0],  hB);

        if (isL1) {
            if (t < TT) {
                // x(t): uniform 32B load
                float xk[DIN];
                float4 xa = reinterpret_cast<const float4*>(xb + t*DIN)[0];
                float4 xc = reinterpret_cast<const float4*>(xb + t*DIN)[1];
                xk[0]=xa.x; xk[1]=xa.y; xk[2]=xa.z; xk[3]=xa.w;
                xk[4]=xc.x; xk[5]=xc.y; xk[6]=xc.z; xk[7]=xc.w;

                // L1 gate row: 40 FMA in 4 chains
                float a0 = bias, a1 = 0.f, a2 = 0.f, a3 = 0.f;
#pragma unroll
                for (int k = 0; k < 32; k += 4) {
                    a0 += wa[k]   * hA[k];
                    a1 += wa[k+1] * hA[k+1];
                    a2 += wa[k+2] * hA[k+2];
                    a3 += wa[k+3] * hA[k+3];
                }
#pragma unroll
                for (int k = 0; k < DIN; k += 4) {
                    a0 += wx[k]   * xk[k];
                    a1 += wx[k+1] * xk[k+1];
                    a2 += wx[k+2] * xk[k+2];
                    a3 += wx[k+3] * xk[k+3];
                }
                const float gg = (a0 + a1) + (a2 + a3);
                float uu = isg ? (gg + gg) : gg;
                float S  = fsig(uu);
                float av = isg ? (S + S - 1.0f) : S;   // tanh(g) | sigmoid

                float ia = __shfl(av, jp);
                float fa = __shfl(av, jp + 16);
                float tg = __shfl(av, jp + 32);
                float oa = __shfl(av, jp + 48);
                c = fa * c + ia * tg;
                float hv = oa * ftanh_(c);
                if (l < 16) hb1[p0][wl*16 + l] = hv;
            }
            if (t >= 2) {
                // out(t-2) column: 32 FMA, off the critical path
                float o0 = obias, o1 = 0.f;
#pragma unroll
                for (int k = 0; k < 32; k += 2) {
                    o0 += wb[k]   * hB[k];
                    o1 += wb[k+1] * hB[k+1];
                }
                if (ostore)
                    outb[(size_t)(t-2)*80 + ocol] = o0 + o1;
            }
        } else {
            if (t >= 1 && t <= TT) {
                // L2 gate row: 64 FMA in 4 chains (h2-part first)
                float a0 = bias, a1 = 0.f, a2 = 0.f, a3 = 0.f;
#pragma unroll
                for (int k = 0; k < 32; k += 4) {
                    a0 += wb[k]   * hB[k];
                    a1 += wb[k+1] * hB[k+1];
                    a2 += wb[k+2] * hB[k+2];
                    a3 += wb[k+3] * hB[k+3];
                }
#pragma unroll
                for (int k = 0; k < 32; k += 4) {
                    a0 += wa[k]   * hA[k];
                    a1 += wa[k+1] * hA[k+1];
                    a2 += wa[k+2] * hA[k+2];
                    a3 += wa[k+3] * hA[k+3];
                }
                const float gg = (a0 + a1) + (a2 + a3);
                float uu = isg ? (gg + gg) : gg;
                float S  = fsig(uu);
                float av = isg ? (S + S - 1.0f) : S;

                float ia = __shfl(av, jp);
                float fa = __shfl(av, jp + 16);
                float tg = __shfl(av, jp + 32);
                float oa = __shfl(av, jp + 48);
                c = fa * c + ia * tg;
                float hv = oa * ftanh_(c);
                if (l < 16) hb2[pm1][wl*16 + l] = hv;   // publish h2(t-1)
            }
        }

        __syncthreads();
    }
}

extern "C" void kernel_launch(void* const* d_in, const int* in_sizes, int n_in,
                              void* d_out, int out_size, void* d_ws, size_t ws_size,
                              hipStream_t stream) {
    const float* x    = (const float*)d_in[0];
    const float* Wih1 = (const float*)d_in[1];
    const float* Whh1 = (const float*)d_in[2];
    const float* bih1 = (const float*)d_in[3];
    const float* bhh1 = (const float*)d_in[4];
    const float* Wih2 = (const float*)d_in[5];
    const float* Whh2 = (const float*)d_in[6];
    const float* bih2 = (const float*)d_in[7];
    const float* bhh2 = (const float*)d_in[8];
    const float* Wlin = (const float*)d_in[9];
    const float* blin = (const float*)d_in[10];

    const int B = in_sizes[0] / (TT * DIN);   // 256

    hipLaunchKernelGGL(lstm_pipe, dim3(B), dim3(256), 0, stream,
                       x, Wih1, Whh1, bih1, bhh1,
                       Wih2, Whh2, bih2, bhh2, Wlin, blin,
                       (float*)d_out);
}

// Round 6
// 442.249 us; speedup vs baseline: 2.2979x; 1.4576x over previous
//
#include <hip/hip_runtime.h>

#define TT  1024
#define DIN 8

// sigma(x) = 1 / (1 + exp2(-x*log2e))
__device__ __forceinline__ float fsig(float x) {
    float e = __builtin_amdgcn_exp2f(-1.4426950408889634f * x);
    return __builtin_amdgcn_rcpf(1.0f + e);
}
// tanh(x) = 2*sigma(2x) - 1
__device__ __forceinline__ float ftanh_(float x) {
    float e = __builtin_amdgcn_exp2f(-2.8853900817779268f * x);
    return 2.0f * __builtin_amdgcn_rcpf(1.0f + e) - 1.0f;
}
// DPP lane permute, compile-time ctrl. 0xB1 = quad_perm(1,0,3,2) (swap 2k<->2k+1)
// 0x114 = row_shr:4 (lane i <- i-4), 0x112 = row_shr:2, 0x102 = row_shl:2 (i <- i+2)
template<int CTRL>
__device__ __forceinline__ float dppf(float v) {
    return __uint_as_float((unsigned)__builtin_amdgcn_update_dpp(
        0, (int)__float_as_uint(v), CTRL, 0xF, 0xF, true));
}

// 8 waves / batch element (block=512), layer-pipelined, 2 lanes per gate row.
// Lane l: ul=l>>3 (unit-local 0..7), g=(l>>1)&3 (i,f,g,o), part=l&1.
// Waves 0-3: layer 1 (16 h-wts + 4 x-wts per lane) + out-linear (16 wts,
//            col = wu*20 + l>>1, lanes<40), out runs 2 steps behind.
// Waves 4-7: layer 2 (32 wts: part0 = Whh2 row (h2 input), part1 = Wih2 (h1)).
// Half-sums combined via DPP quad_perm; cell update via DPP row_shr4/shr2/shl2
// onto the g-lanes (l&7 in {4,5}); lane l&7==4 publishes h to LDS.
// Pipeline at iter t: L1 -> h1(t); L2 -> h2(t-1); out(t-2). One barrier/iter.
__global__ void __launch_bounds__(512, 2)
lstm_pipe8(const float* __restrict__ x,
           const float* __restrict__ Wih1, const float* __restrict__ Whh1,
           const float* __restrict__ bih1, const float* __restrict__ bhh1,
           const float* __restrict__ Wih2, const float* __restrict__ Whh2,
           const float* __restrict__ bih2, const float* __restrict__ bhh2,
           const float* __restrict__ Wlin, const float* __restrict__ blin,
           float* __restrict__ out)
{
    const int tid  = threadIdx.x;
    const int wv   = tid >> 6;         // wave 0..7
    const int l    = tid & 63;
    const int part = l & 1;
    const int g    = (l >> 1) & 3;     // 0=i 1=f 2=g 3=o
    const int ul   = l >> 3;           // unit-local 0..7
    const int b    = blockIdx.x;
    const bool isL1 = (wv < 4);
    const int  wu   = isL1 ? wv : (wv - 4);
    const int  unit = wu*8 + ul;       // hidden unit 0..31
    const int  R    = g*32 + unit;     // gate row 0..127
    const bool isg  = (g == 2);

    __shared__ float hb1[2][32];       // h1 by parity
    __shared__ float hb2[2][32];       // h2 by parity
    if (tid < 64)       ((float*)hb1)[tid]      = 0.f;
    else if (tid < 128) ((float*)hb2)[tid - 64] = 0.f;

    // ---- per-lane weights ----
    float wg[20];          // L1: [0:16]=Whh1 half, [16:20]=Wih1 quarter
    float wg2[32];         // L2: full 32 input wts
    float wl[16];          // L1: out-linear half column
    float bias = 0.f, obias = 0.f;
    int ocol = 0;

    if (isL1) {
        const float* wsrc = Whh1 + R*32 + part*16;
#pragma unroll
        for (int qq = 0; qq < 4; ++qq) {
            float4 v = reinterpret_cast<const float4*>(wsrc)[qq];
            wg[4*qq]=v.x; wg[4*qq+1]=v.y; wg[4*qq+2]=v.z; wg[4*qq+3]=v.w;
        }
        float4 xv = *reinterpret_cast<const float4*>(Wih1 + R*DIN + part*4);
        wg[16]=xv.x; wg[17]=xv.y; wg[18]=xv.z; wg[19]=xv.w;
        if (!part) bias = bih1[R] + bhh1[R];
        ocol = wu*20 + (l >> 1);
        const int oc = (l < 40) ? ocol : 79;       // clamp: loads valid, unused
        const float* osrc = Wlin + oc*32 + part*16;
#pragma unroll
        for (int qq = 0; qq < 4; ++qq) {
            float4 v = reinterpret_cast<const float4*>(osrc)[qq];
            wl[4*qq]=v.x; wl[4*qq+1]=v.y; wl[4*qq+2]=v.z; wl[4*qq+3]=v.w;
        }
        if (!part) obias = blin[oc];
    } else {
        const float* wsrc = part ? (Wih2 + R*32) : (Whh2 + R*32);
#pragma unroll
        for (int qq = 0; qq < 8; ++qq) {
            float4 v = reinterpret_cast<const float4*>(wsrc)[qq];
            wg2[4*qq]=v.x; wg2[4*qq+1]=v.y; wg2[4*qq+2]=v.z; wg2[4*qq+3]=v.w;
        }
        if (!part) bias = bih2[R] + bhh2[R];
    }

    float c = 0.f;   // valid on lanes l&7 in {4,5}; bounded garbage elsewhere

    const float* __restrict__ xb = x   + (size_t)b * (TT*DIN);
    float* __restrict__ outb     = out + (size_t)b * (TT*80);

    float4 xcur;
    if (isL1) xcur = *reinterpret_cast<const float4*>(xb + part*4);  // x(0) half

    __syncthreads();   // zero-init + weights visible

#pragma unroll 1
    for (int t = 0; t <= TT + 1; ++t) {
        const int pm1 = (t - 1) & 1;
        const int p0  = t & 1;

        if (isL1) {
            if (t < TT) {
                // L1 gate half-row: 16 h-FMA + 4 x-FMA
                const float* hin = &hb1[pm1][part << 4];
                float a0 = bias, a1 = 0.f, a2 = 0.f, a3 = 0.f;
#pragma unroll
                for (int qq = 0; qq < 4; ++qq) {
                    float4 v = reinterpret_cast<const float4*>(hin)[qq];
                    a0 += wg[4*qq]  *v.x; a1 += wg[4*qq+1]*v.y;
                    a2 += wg[4*qq+2]*v.z; a3 += wg[4*qq+3]*v.w;
                }
                a0 += wg[16]*xcur.x; a1 += wg[17]*xcur.y;
                a2 += wg[18]*xcur.z; a3 += wg[19]*xcur.w;
                // prefetch next x half (latency hides across barrier)
                const int tn = (t + 1 < TT) ? (t + 1) : (TT - 1);
                xcur = *reinterpret_cast<const float4*>(xb + tn*DIN + part*4);

                float sum  = (a0 + a1) + (a2 + a3);
                float full = sum + dppf<0xB1>(sum);      // combine half-dots
                float u  = isg ? (full + full) : full;
                float S  = fsig(u);
                float av = isg ? (S + S - 1.0f) : S;     // tanh(g) | sigmoid
                // cell update on g-lanes (l&7 in {4,5}) via DPP
                float itg = dppf<0x114>(av) * av;        // sig(i)*tanh(g)
                float fv  = dppf<0x112>(av);             // sig(f)
                c = fv * c + itg;
                float so  = dppf<0x102>(av);             // sig(o)
                float hv  = so * ftanh_(c);
                if ((l & 7) == 4) hb1[p0][unit] = hv;    // publish h1(t)
            }
            if (t >= 2) {
                // out(t-2) half-column: 16 FMA
                const float* hob = &hb2[p0][part << 4];
                float o0 = obias, o1 = 0.f, o2 = 0.f, o3 = 0.f;
#pragma unroll
                for (int qq = 0; qq < 4; ++qq) {
                    float4 v = reinterpret_cast<const float4*>(hob)[qq];
                    o0 += wl[4*qq]  *v.x; o1 += wl[4*qq+1]*v.y;
                    o2 += wl[4*qq+2]*v.z; o3 += wl[4*qq+3]*v.w;
                }
                float osum  = (o0 + o1) + (o2 + o3);
                float ofull = osum + dppf<0xB1>(osum);
                if (!part && l < 40)
                    outb[(size_t)(t - 2)*80 + ocol] = ofull;
            }
        } else {
            if (t >= 1 && t <= TT) {
                // L2 gate half-row: 32 FMA (part0: h2(t-2) wts, part1: h1(t-1))
                const float* hin = part ? &hb1[pm1][0] : &hb2[p0][0];
                float a0 = bias, a1 = 0.f, a2 = 0.f, a3 = 0.f;
#pragma unroll
                for (int qq = 0; qq < 8; ++qq) {
                    float4 v = reinterpret_cast<const float4*>(hin)[qq];
                    a0 += wg2[4*qq]  *v.x; a1 += wg2[4*qq+1]*v.y;
                    a2 += wg2[4*qq+2]*v.z; a3 += wg2[4*qq+3]*v.w;
                }
                float sum  = (a0 + a1) + (a2 + a3);
                float full = sum + dppf<0xB1>(sum);
                float u  = isg ? (full + full) : full;
                float S  = fsig(u);
                float av = isg ? (S + S - 1.0f) : S;
                float itg = dppf<0x114>(av) * av;
                float fv  = dppf<0x112>(av);
                c = fv * c + itg;
                float so  = dppf<0x102>(av);
                float hv  = so * ftanh_(c);
                if ((l & 7) == 4) hb2[pm1][unit] = hv;   // publish h2(t-1)
            }
        }

        __syncthreads();
    }
}

extern "C" void kernel_launch(void* const* d_in, const int* in_sizes, int n_in,
                              void* d_out, int out_size, void* d_ws, size_t ws_size,
                              hipStream_t stream) {
    const float* x    = (const float*)d_in[0];
    const float* Wih1 = (const float*)d_in[1];
    const float* Whh1 = (const float*)d_in[2];
    const float* bih1 = (const float*)d_in[3];
    const float* bhh1 = (const float*)d_in[4];
    const float* Wih2 = (const float*)d_in[5];
    const float* Whh2 = (const float*)d_in[6];
    const float* bih2 = (const float*)d_in[7];
    const float* bhh2 = (const float*)d_in[8];
    const float* Wlin = (const float*)d_in[9];
    const float* blin = (const float*)d_in[10];

    const int B = in_sizes[0] / (TT * DIN);   // 256

    hipLaunchKernelGGL(lstm_pipe8, dim3(B), dim3(512), 0, stream,
                       x, Wih1, Whh1, bih1, bhh1,
                       Wih2, Whh2, bih2, bhh2, Wlin, blin,
                       (float*)d_out);
}